// Round 4
// baseline (151.587 us; speedup 1.0000x reference)
//
#include <hip/hip_runtime.h>

// Single-scale fixed-size deformable attention.
// value:  (BS, H*W, NH, HD) f32
// sloc:   (BS, NQ, NH, 1, NP, 2) f32  (locations in [0,1])
// aw:     (BS, NQ, NH, 1, NP) f32
// out:    (BS, NQ, NH*HD) f32

constexpr int BS = 4, NQ = 10000, NH = 8, HD = 32, NP = 4, H = 100, W = 100;
constexpr int HW = H * W;
constexpr int NGROUP = BS * NQ * NH;            // 320,000 (b,q,h) groups
constexpr int LANES_PER_GROUP = 8;              // each lane: 4 channels (float4)

// Native clang vector type — required by __builtin_nontemporal_* (HIP_vector_type is not).
typedef float f32x4 __attribute__((ext_vector_type(4)));

__global__ __launch_bounds__(256)
void deform_attn_kernel(const float* __restrict__ value,
                        const float* __restrict__ sloc,
                        const float* __restrict__ aw,
                        float* __restrict__ out)
{
    const int tid   = blockIdx.x * 256 + threadIdx.x;
    const int group = tid >> 3;                 // (b*NQ + q)*NH + h
    const int lane  = tid & 7;
    if (group >= NGROUP) return;

    const int h  = group & (NH - 1);
    const int bq = group >> 3;                  // b*NQ + q
    const int b  = bq / NQ;

    // Per-group parameters (wave-broadcast loads; 8 lanes share each address).
    // Non-temporal: touch-once streams, keep L2 for the value map.
    const f32x4 l01 = __builtin_nontemporal_load((const f32x4*)(sloc + (size_t)group * (NP * 2)));
    const f32x4 l23 = __builtin_nontemporal_load((const f32x4*)(sloc + (size_t)group * (NP * 2) + 4));
    const f32x4 wv  = __builtin_nontemporal_load((const f32x4*)(aw   + (size_t)group * NP));

    const float lx[NP] = {l01.x, l01.z, l23.x, l23.z};
    const float ly[NP] = {l01.y, l01.w, l23.y, l23.w};
    const float wp[NP] = {wv.x,  wv.y,  wv.z,  wv.w};

    // Base pointer for this (b, h, channel-quad); spatial index s adds s*NH*HD
    const float* vbase = value + (size_t)b * HW * NH * HD + h * HD + lane * 4;

    f32x4 acc = (f32x4)(0.f);

#pragma unroll
    for (int p = 0; p < NP; ++p) {
        // grid = 2*loc-1; unnormalize align_corners=False: x = loc*W - 0.5
        const float x = lx[p] * (float)W - 0.5f;
        const float y = ly[p] * (float)H - 0.5f;
        const float x0f = floorf(x);
        const float y0f = floorf(y);
        const int   x0  = (int)x0f, y0 = (int)y0f;
        const int   x1  = x0 + 1,   y1 = y0 + 1;
        const float wx1 = x - x0f,  wx0 = 1.f - wx1;
        const float wy1 = y - y0f,  wy0 = 1.f - wy1;

        const bool vx0 = (unsigned)x0 < (unsigned)W;
        const bool vx1 = (unsigned)x1 < (unsigned)W;
        const bool vy0 = (unsigned)y0 < (unsigned)H;
        const bool vy1 = (unsigned)y1 < (unsigned)H;

        const int xc0 = min(max(x0, 0), W - 1);
        const int xc1 = min(max(x1, 0), W - 1);
        const int yc0 = min(max(y0, 0), H - 1);
        const int yc1 = min(max(y1, 0), H - 1);

        // zeros padding: invalid corner -> weight 0 (load stays in-bounds via clamp)
        const float w00 = (vx0 && vy0) ? wp[p] * wx0 * wy0 : 0.f;
        const float w10 = (vx1 && vy0) ? wp[p] * wx1 * wy0 : 0.f;
        const float w01 = (vx0 && vy1) ? wp[p] * wx0 * wy1 : 0.f;
        const float w11 = (vx1 && vy1) ? wp[p] * wx1 * wy1 : 0.f;

        const f32x4 v00 = *(const f32x4*)(vbase + (size_t)(yc0 * W + xc0) * (NH * HD));
        const f32x4 v10 = *(const f32x4*)(vbase + (size_t)(yc0 * W + xc1) * (NH * HD));
        const f32x4 v01 = *(const f32x4*)(vbase + (size_t)(yc1 * W + xc0) * (NH * HD));
        const f32x4 v11 = *(const f32x4*)(vbase + (size_t)(yc1 * W + xc1) * (NH * HD));

        acc += w00 * v00 + w10 * v10 + w01 * v01 + w11 * v11;
    }

    // out[b, q, h*HD + lane*4 ..] — consecutive groups/lanes -> contiguous store.
    // Non-temporal: written once, never re-read by this kernel.
    __builtin_nontemporal_store(acc, (f32x4*)(out + (size_t)bq * (NH * HD) + h * HD + lane * 4));
}

extern "C" void kernel_launch(void* const* d_in, const int* in_sizes, int n_in,
                              void* d_out, int out_size, void* d_ws, size_t ws_size,
                              hipStream_t stream) {
    const float* value = (const float*)d_in[0];
    // d_in[1] = value_spatial_shapes (int64) — unused in fixed-size variant
    const float* sloc  = (const float*)d_in[2];
    const float* aw    = (const float*)d_in[3];
    float*       out   = (float*)d_out;

    const int total_threads = NGROUP * LANES_PER_GROUP;   // 2,560,000
    const int block = 256;
    const int grid  = (total_threads + block - 1) / block; // 10,000
    deform_attn_kernel<<<grid, block, 0, stream>>>(value, sloc, aw, out);
}

// Round 5
// 134.918 us; speedup vs baseline: 1.1235x; 1.1235x over previous
//
#include <hip/hip_runtime.h>

// Single-scale fixed-size deformable attention.
// value:  (BS, H*W, NH, HD) f32
// sloc:   (BS, NQ, NH, 1, NP, 2) f32  (locations in [0,1])
// aw:     (BS, NQ, NH, 1, NP) f32
// out:    (BS, NQ, NH*HD) f32
//
// R4 baseline: 68.7us, FETCH 226MB (4x compulsory), VALU 21%, BW 48% peak.
// R5: (b,h)-major group ordering + XCD chunk swizzle -> each XCD streams
// 4 value slabs of 1.28MB sequentially (slab fits 4MB XCD L2).

constexpr int BS = 4, NQ = 10000, NH = 8, HD = 32, NP = 4, H = 100, W = 100;
constexpr int HW = H * W;
constexpr int NGROUP = BS * NQ * NH;            // 320,000 (b,h,q) groups
constexpr int NXCD = 8;

typedef float f32x4 __attribute__((ext_vector_type(4)));

__global__ __launch_bounds__(256)
void deform_attn_kernel(const float* __restrict__ value,
                        const float* __restrict__ sloc,
                        const float* __restrict__ aw,
                        float* __restrict__ out)
{
    // XCD-aware swizzle: grid=10000, 10000%8==0 -> bijective chunk mapping.
    // XCD x (= blockIdx.x % 8 by default dispatch) gets logical blocks
    // [x*1250, (x+1)*1250) = exactly 4 (b,h) slabs of the value map.
    const int chunk = gridDim.x >> 3;                    // 1250
    const int swz   = (blockIdx.x & (NXCD - 1)) * chunk + (blockIdx.x >> 3);

    const int tid   = swz * 256 + (int)threadIdx.x;
    const int group = tid >> 3;                          // (b*NH + h)*NQ + q
    const int lane  = tid & 7;
    if (group >= NGROUP) return;

    // (b,h)-major, q-minor decomposition (compiler emits magic-mul for /NQ)
    const int q  = group % NQ;
    const int bh = group / NQ;                           // b*NH + h
    const int h  = bh & (NH - 1);
    const int b  = bh >> 3;
    const int bq = b * NQ + q;

    // Per-group params: 8 lanes broadcast-load the same 48B. Indexed by
    // (b,q,h) layout of sloc/aw. These lines are REUSED across the 4 h-passes
    // of this XCD's chunk -> keep them cacheable (no nontemporal).
    const size_t pbase = ((size_t)bq * NH + h);
    const f32x4 l01 = *(const f32x4*)(sloc + pbase * (NP * 2));
    const f32x4 l23 = *(const f32x4*)(sloc + pbase * (NP * 2) + 4);
    const f32x4 wv  = *(const f32x4*)(aw   + pbase * NP);

    const float lx[NP] = {l01.x, l01.z, l23.x, l23.z};
    const float ly[NP] = {l01.y, l01.w, l23.y, l23.w};
    const float wp[NP] = {wv.x,  wv.y,  wv.z,  wv.w};

    // Base pointer for this (b, h, channel-quad); spatial index s adds s*NH*HD
    const float* vbase = value + (size_t)b * HW * NH * HD + h * HD + lane * 4;

    f32x4 acc = (f32x4)(0.f);

#pragma unroll
    for (int p = 0; p < NP; ++p) {
        // grid = 2*loc-1; unnormalize align_corners=False: x = loc*W - 0.5
        const float x = lx[p] * (float)W - 0.5f;
        const float y = ly[p] * (float)H - 0.5f;
        const float x0f = floorf(x);
        const float y0f = floorf(y);
        const int   x0  = (int)x0f, y0 = (int)y0f;
        const int   x1  = x0 + 1,   y1 = y0 + 1;
        const float wx1 = x - x0f,  wx0 = 1.f - wx1;
        const float wy1 = y - y0f,  wy0 = 1.f - wy1;

        const bool vx0 = (unsigned)x0 < (unsigned)W;
        const bool vx1 = (unsigned)x1 < (unsigned)W;
        const bool vy0 = (unsigned)y0 < (unsigned)H;
        const bool vy1 = (unsigned)y1 < (unsigned)H;

        const int xc0 = min(max(x0, 0), W - 1);
        const int xc1 = min(max(x1, 0), W - 1);
        const int yc0 = min(max(y0, 0), H - 1);
        const int yc1 = min(max(y1, 0), H - 1);

        // zeros padding: invalid corner -> weight 0 (load stays in-bounds via clamp)
        const float w00 = (vx0 && vy0) ? wp[p] * wx0 * wy0 : 0.f;
        const float w10 = (vx1 && vy0) ? wp[p] * wx1 * wy0 : 0.f;
        const float w01 = (vx0 && vy1) ? wp[p] * wx0 * wy1 : 0.f;
        const float w11 = (vx1 && vy1) ? wp[p] * wx1 * wy1 : 0.f;

        const f32x4 v00 = *(const f32x4*)(vbase + (size_t)(yc0 * W + xc0) * (NH * HD));
        const f32x4 v10 = *(const f32x4*)(vbase + (size_t)(yc0 * W + xc1) * (NH * HD));
        const f32x4 v01 = *(const f32x4*)(vbase + (size_t)(yc1 * W + xc0) * (NH * HD));
        const f32x4 v11 = *(const f32x4*)(vbase + (size_t)(yc1 * W + xc1) * (NH * HD));

        acc += w00 * v00 + w10 * v10 + w01 * v01 + w11 * v11;
    }

    // out[b, q, h*HD + lane*4 ..]: each group writes one full 128B line
    // (128B-aligned). Nontemporal: written once, never re-read.
    __builtin_nontemporal_store(acc, (f32x4*)(out + (size_t)bq * (NH * HD) + h * HD + lane * 4));
}

extern "C" void kernel_launch(void* const* d_in, const int* in_sizes, int n_in,
                              void* d_out, int out_size, void* d_ws, size_t ws_size,
                              hipStream_t stream) {
    const float* value = (const float*)d_in[0];
    // d_in[1] = value_spatial_shapes (int64) — unused in fixed-size variant
    const float* sloc  = (const float*)d_in[2];
    const float* aw    = (const float*)d_in[3];
    float*       out   = (float*)d_out;

    const int total_threads = NGROUP * 8;                  // 2,560,000
    const int block = 256;
    const int grid  = (total_threads + block - 1) / block; // 10,000 (%8==0)
    deform_attn_kernel<<<grid, block, 0, stream>>>(value, sloc, aw, out);
}